// Round 3
// baseline (359.294 us; speedup 1.0000x reference)
//
#include <hip/hip_runtime.h>
#include <math.h>

#define NROWS 16384     // B*S
#define DDIM  256
#define NTILES 50       // 6400 padded codeword columns
#define L0_END  5832
#define L1_BASE 5888    // tile 46
#define L1_END  6212
#define L2_BASE 6272    // tile 49
#define L2_END  6290

typedef __attribute__((ext_vector_type(8))) short bf16x8;
typedef __attribute__((ext_vector_type(4))) float f32x4;
typedef __attribute__((ext_vector_type(4))) unsigned short us4;

__device__ __forceinline__ unsigned short bf16_rne(float f) {
  unsigned x = __float_as_uint(f);
  unsigned r = x + 0x7fffu + ((x >> 16) & 1u);
  return (unsigned short)(r >> 16);
}

typedef __attribute__((address_space(3))) unsigned int lds_uint;
typedef __attribute__((address_space(1))) const unsigned int glb_uint;
__device__ __forceinline__ void gload16(const void* g, void* l) {
  __builtin_amdgcn_global_load_lds((glb_uint*)g, (lds_uint*)l, 16, 0, 0);
}

__device__ __forceinline__ bool lexless(float av, int ai, float bv, int bi) {
  return (av < bv) || (av == bv && ai < bi);
}
// merge sorted pair (a1<=a2) with sorted pair (b1<=b2) -> sorted top-2 in a
__device__ __forceinline__ void merge_pair(float& a1, int& a1i, float& a2, int& a2i,
                                           float b1, int b1i, float b2, int b2i) {
  if (lexless(b1, b1i, a1, a1i)) {
    float t1 = a1; int t1i = a1i;
    a1 = b1; a1i = b1i;
    if (lexless(b2, b2i, t1, t1i)) { a2 = b2; a2i = b2i; }
    else                           { a2 = t1; a2i = t1i; }
  } else {
    if (lexless(b1, b1i, a2, a2i)) { a2 = b1; a2i = b1i; }
  }
}

// sorted-8 insertion (fully unrolled -> stays in registers)
__device__ __forceinline__ void insert8(float* bv, int* bi, float v, int i) {
  bool q[8];
  #pragma unroll
  for (int k = 0; k < 8; ++k) q[k] = lexless(v, i, bv[k], bi[k]);
  #pragma unroll
  for (int k = 7; k >= 1; --k) {
    bv[k] = q[k] ? (q[k - 1] ? bv[k - 1] : v) : bv[k];
    bi[k] = q[k] ? (q[k - 1] ? bi[k - 1] : i) : bi[k];
  }
  if (q[0]) { bv[0] = v; bi[0] = i; }
}

// ---------------- embeds -> bf16 hi ----------------
__global__ __launch_bounds__(256) void split_embeds(const float* __restrict__ e,
                                                    unsigned short* __restrict__ ehi) {
  int gid = blockIdx.x * 256 + threadIdx.x;            // 524288 threads, 8 floats each
  const float4* p = reinterpret_cast<const float4*>(e) + (size_t)gid * 2;
  float4 a = p[0], b = p[1];
  float f[8] = {a.x, a.y, a.z, a.w, b.x, b.y, b.z, b.w};
  unsigned short hi[8];
  #pragma unroll
  for (int i = 0; i < 8; ++i) hi[i] = bf16_rne(f[i]);
  us4 h0 = {hi[0], hi[1], hi[2], hi[3]}, h1 = {hi[4], hi[5], hi[6], hi[7]};
  *reinterpret_cast<us4*>(&ehi[(size_t)gid * 8]) = h0;
  *reinterpret_cast<us4*>(&ehi[(size_t)gid * 8 + 4]) = h1;
}

// ------------- padded W hi + squared norms -------------
__global__ __launch_bounds__(256) void prep_w(const float* __restrict__ cb0,
                                              const float* __restrict__ cb1,
                                              const float* __restrict__ cb2,
                                              unsigned short* __restrict__ whi,
                                              float* __restrict__ wsq) {
  int wv = threadIdx.x >> 6, ln = threadIdx.x & 63;
  int p = blockIdx.x * 4 + wv;                          // 0..6399
  const float* src = nullptr; int local = 0;
  if (p < L0_END)                        { src = cb0; local = p; }
  else if (p >= L1_BASE && p < L1_END)   { src = cb1; local = p - L1_BASE; }
  else if (p >= L2_BASE && p < L2_END)   { src = cb2; local = p - L2_BASE; }
  float4 f = make_float4(0.f, 0.f, 0.f, 0.f);
  if (src) f = *reinterpret_cast<const float4*>(src + (size_t)local * DDIM + ln * 4);
  us4 h = {bf16_rne(f.x), bf16_rne(f.y), bf16_rne(f.z), bf16_rne(f.w)};
  *reinterpret_cast<us4*>(&whi[(size_t)p * DDIM + ln * 4]) = h;
  float s = f.x * f.x + f.y * f.y + f.z * f.z + f.w * f.w;
  #pragma unroll
  for (int m = 32; m > 0; m >>= 1) s += __shfl_xor(s, m);
  if (ln == 0) wsq[p] = src ? s : INFINITY;
}

// ------------- hi-only MFMA GEMM (K=256) + per-tile top-2 -------------
// grid 128 mtiles x 50 ntiles; 4 waves (2x2), tile 128x128, BK=32,
// double-buffered LDS (1 barrier/step), both-sides chunk swizzle.
__global__ __launch_bounds__(256, 2) void gemm_top2(
    const unsigned short* __restrict__ Ehi, const unsigned short* __restrict__ Whi,
    const float* __restrict__ wsq,
    float2* __restrict__ pv, int2* __restrict__ pi) {
  __shared__ unsigned short As[2][128 * 32];   // 2 x 8 KB
  __shared__ unsigned short Bs[2][128 * 32];   // 2 x 8 KB
  __shared__ float4 epi2[2][128];              // 4 KB

  const int tid = threadIdx.x;
  const int wv = tid >> 6, ln = tid & 63;
  const int mt = blockIdx.x & 127, nt = blockIdx.x >> 7;
  const int wm = wv >> 1, wn = wv & 1;
  const int t = ln & 15, g = ln >> 4;

  // per-lane staging source (swizzled chunk): lds slot e holds (row=e>>2, chunk=(e&3)^((row>>1)&3))
  int srow[2], soff[2];
  #pragma unroll
  for (int c = 0; c < 2; ++c) {
    int e = (wv * 2 + c) * 64 + ln;
    int row = e >> 2;
    int cs = (e & 3) ^ ((row >> 1) & 3);
    srow[c] = row;
    soff[c] = cs * 8;
  }

#define STAGE(buf, k0) do {                                                        \
    _Pragma("unroll")                                                              \
    for (int c = 0; c < 2; ++c) {                                                  \
      gload16(Ehi + ((size_t)(mt * 128 + srow[c])) * DDIM + (k0) + soff[c],        \
              &As[buf][(wv * 2 + c) * 512]);                                       \
      gload16(Whi + ((size_t)(nt * 128 + srow[c])) * DDIM + (k0) + soff[c],        \
              &Bs[buf][(wv * 2 + c) * 512]);                                       \
    } } while (0)

  f32x4 acc[4][4];
  #pragma unroll
  for (int i = 0; i < 4; ++i)
    #pragma unroll
    for (int j = 0; j < 4; ++j) acc[i][j] = (f32x4){0.f, 0.f, 0.f, 0.f};

  STAGE(0, 0);
  __syncthreads();                            // buf0 staged (vmcnt drained)
  for (int s = 0; s < 8; ++s) {
    const int cur = s & 1;
    if (s < 7) STAGE(cur ^ 1, (s + 1) << 5);  // issue next tile EARLY
    bf16x8 af[4], bfr[4];
    #pragma unroll
    for (int i = 0; i < 4; ++i) {
      int r = wm * 64 + i * 16 + t;
      af[i] = *reinterpret_cast<const bf16x8*>(&As[cur][r * 32 + ((g ^ ((r >> 1) & 3)) << 3)]);
    }
    #pragma unroll
    for (int j = 0; j < 4; ++j) {
      int r = wn * 64 + j * 16 + t;
      bfr[j] = *reinterpret_cast<const bf16x8*>(&Bs[cur][r * 32 + ((g ^ ((r >> 1) & 3)) << 3)]);
    }
    #pragma unroll
    for (int i = 0; i < 4; ++i)
      #pragma unroll
      for (int j = 0; j < 4; ++j)
        acc[i][j] = __builtin_amdgcn_mfma_f32_16x16x32_bf16(af[i], bfr[j], acc[i][j], 0, 0, 0);
    __syncthreads();                          // next-tile loads landed + readers done
  }
#undef STAGE

  // epilogue: dist = wsq - 2*score; per-row top-2 (lexicographic => first-index ties)
  const int colbase = nt * 128 + wn * 64;
  float wq[4];
  #pragma unroll
  for (int j = 0; j < 4; ++j) wq[j] = wsq[colbase + j * 16 + t];

  #pragma unroll
  for (int i = 0; i < 4; ++i) {
    #pragma unroll
    for (int r = 0; r < 4; ++r) {
      float b1 = INFINITY, b2 = INFINITY; int b1i = -1, b2i = -1;
      #pragma unroll
      for (int j = 0; j < 4; ++j) {
        float dv = fmaf(-2.0f, acc[i][j][r], wq[j]);
        int cj = colbase + j * 16 + t;
        if (dv < b1)      { b2 = b1; b2i = b1i; b1 = dv; b1i = cj; }
        else if (dv < b2) { b2 = dv; b2i = cj; }
      }
      #pragma unroll
      for (int m = 1; m < 16; m <<= 1) {
        float o1 = __shfl_xor(b1, m); int o1i = __shfl_xor(b1i, m);
        float o2 = __shfl_xor(b2, m); int o2i = __shfl_xor(b2i, m);
        merge_pair(b1, b1i, b2, b2i, o1, o1i, o2, o2i);
      }
      if (t == 0)
        epi2[wn][wm * 64 + i * 16 + g * 4 + r] =
            make_float4(b1, b2, __int_as_float(b1i), __int_as_float(b2i));
    }
  }
  __syncthreads();
  if (tid < 128) {
    float4 h0 = epi2[0][tid], h1 = epi2[1][tid];
    float a1 = h0.x, a2 = h0.y; int a1i = __float_as_int(h0.z), a2i = __float_as_int(h0.w);
    merge_pair(a1, a1i, a2, a2i, h1.x, __float_as_int(h1.z), h1.y, __float_as_int(h1.w));
    int orow = mt * 128 + tid;
    pv[(size_t)nt * NROWS + orow] = make_float2(a1, a2);
    pi[(size_t)nt * NROWS + orow] = make_int2(a1i, a2i);
  }
}

// ------------- merge per-tile top-2 into per-layer top-8 -------------
__global__ __launch_bounds__(256) void merge_tiles(const float2* __restrict__ pv,
                                                   const int2* __restrict__ pi,
                                                   int* __restrict__ ci8) {
  int gid = blockIdx.x * 256 + threadIdx.x;       // 49152
  int layer = gid >> 14, row = gid & (NROWS - 1);
  int nt0 = (layer == 0) ? 0 : ((layer == 1) ? 46 : 49);
  int nt1 = (layer == 0) ? 46 : ((layer == 1) ? 49 : 50);
  float bv[8]; int bi[8];
  #pragma unroll
  for (int k = 0; k < 8; ++k) { bv[k] = INFINITY; bi[k] = -1; }
  for (int nt = nt0; nt < nt1; ++nt) {
    float2 v = pv[(size_t)nt * NROWS + row];
    int2 ix = pi[(size_t)nt * NROWS + row];
    insert8(bv, bi, v.x, ix.x);
    insert8(bv, bi, v.y, ix.y);
  }
  #pragma unroll
  for (int k = 0; k < 8; ++k) ci8[(size_t)gid * 8 + k] = bi[k];
}

// ------------- exact fp64 rescore of 8 candidates + gather + loss -------------
__global__ __launch_bounds__(256) void rescore(const float* __restrict__ embeds,
                                               const float* __restrict__ cb0,
                                               const float* __restrict__ cb1,
                                               const float* __restrict__ cb2,
                                               const int* __restrict__ ci8,
                                               float* __restrict__ out,
                                               float* __restrict__ lossp) {
  const int wv = threadIdx.x >> 6, ln = threadIdx.x & 63;
  const int gid = blockIdx.x * 4 + wv;            // 0..49151
  const int layer = gid >> 14, row = gid & (NROWS - 1);
  const float* cb = (layer == 0) ? cb0 : ((layer == 1) ? cb1 : cb2);
  const int base = (layer == 0) ? 0 : ((layer == 1) ? L1_BASE : L2_BASE);
  const int K    = (layer == 0) ? 5832 : ((layer == 1) ? 324 : 18);
  float4 e = *reinterpret_cast<const float4*>(embeds + (size_t)row * DDIM + ln * 4);
  double d[8]; float4 w[8]; int kk[8];
  #pragma unroll
  for (int c = 0; c < 8; ++c) {
    int raw = ci8[(size_t)gid * 8 + c];
    int k = raw - base;
    bool valid = (raw >= 0) && (k >= 0) && (k < K);
    kk[c] = valid ? k : 0x7fffffff;
    int ks = valid ? k : 0;
    float4 wc = *reinterpret_cast<const float4*>(cb + (size_t)ks * DDIM + ln * 4);
    w[c] = wc;
    double x0 = (double)e.x - wc.x, x1 = (double)e.y - wc.y;
    double x2 = (double)e.z - wc.z, x3 = (double)e.w - wc.w;
    double s = x0 * x0 + x1 * x1 + x2 * x2 + x3 * x3;
    d[c] = valid ? s : (double)INFINITY;
  }
  #pragma unroll
  for (int m = 32; m > 0; m >>= 1) {
    #pragma unroll
    for (int c = 0; c < 8; ++c) d[c] += __shfl_xor(d[c], m);
  }
  double bd = d[0]; int bk = kk[0]; int bc = 0;
  #pragma unroll
  for (int c = 1; c < 8; ++c) {
    bool better = (d[c] < bd) || (d[c] == bd && kk[c] < bk);
    bd = better ? d[c] : bd;
    bk = better ? kk[c] : bk;
    bc = better ? c : bc;
  }
  float4 q = w[0];
  #pragma unroll
  for (int c = 1; c < 8; ++c) if (bc == c) q = w[c];
  *reinterpret_cast<float4*>(out + (size_t)gid * DDIM + ln * 4) = q;
  __shared__ float red[4];
  if (ln == 0) red[wv] = (float)bd;
  __syncthreads();
  if (threadIdx.x == 0) lossp[blockIdx.x] = red[0] + red[1] + red[2] + red[3];
}

__global__ __launch_bounds__(256) void loss_reduce(const float* __restrict__ lossp,
                                                   float* __restrict__ outloss) {
  __shared__ float red[256];
  const int tid = threadIdx.x;
  float s = 0.f;
  for (int i = tid; i < 12288; i += 256) s += lossp[i];
  red[tid] = s;
  __syncthreads();
  for (int st = 128; st > 0; st >>= 1) {
    if (tid < st) red[tid] += red[tid + st];
    __syncthreads();
  }
  if (tid == 0) outloss[0] = red[0] * (1.25f / ((float)NROWS * (float)DDIM));
}

extern "C" void kernel_launch(void* const* d_in, const int* in_sizes, int n_in,
                              void* d_out, int out_size, void* d_ws, size_t ws_size,
                              hipStream_t stream) {
  const float* embeds = (const float*)d_in[0];
  const float* cb0    = (const float*)d_in[1];
  const float* cb1    = (const float*)d_in[2];
  const float* cb2    = (const float*)d_in[3];
  float* out  = (float*)d_out;
  float* loss = out + (size_t)3 * NROWS * DDIM;

  char* ws = (char*)d_ws;
  unsigned short* Ehi = (unsigned short*)(ws);                   //  8,388,608 B
  unsigned short* Whi = (unsigned short*)(ws + 8388608);         //  3,276,800 B
  float*          wsq = (float*)(ws + 11665408);                 //     25,600 B
  float2*         pv  = (float2*)(ws + 11691008);                //  6,553,600 B
  int2*           pi  = (int2*)(ws + 18244608);                  //  6,553,600 B
  int*            ci8 = (int*)(ws + 24798208);                   //  1,572,864 B
  float*          lp  = (float*)(ws + 26371072);                 //     49,152 B

  (void)in_sizes; (void)n_in; (void)out_size; (void)ws_size;

  split_embeds<<<2048, 256, 0, stream>>>(embeds, Ehi);
  prep_w<<<1600, 256, 0, stream>>>(cb0, cb1, cb2, Whi, wsq);
  gemm_top2<<<128 * NTILES, 256, 0, stream>>>(Ehi, Whi, wsq, pv, pi);
  merge_tiles<<<192, 256, 0, stream>>>(pv, pi, ci8);
  rescore<<<12288, 256, 0, stream>>>(embeds, cb0, cb1, cb2, ci8, out, lp);
  loss_reduce<<<1, 256, 0, stream>>>(lp, loss);
}

// Round 4
// 185.737 us; speedup vs baseline: 1.9344x; 1.9344x over previous
//
#include <hip/hip_runtime.h>
#include <math.h>

#define NROWS 16384
#define DDIM  256

typedef __attribute__((ext_vector_type(8))) short bf16x8;
typedef __attribute__((ext_vector_type(4))) float f32x4;
typedef __attribute__((ext_vector_type(4))) unsigned short us4;

__device__ __forceinline__ unsigned short bf16_rne(float f) {
  unsigned x = __float_as_uint(f);
  unsigned r = x + 0x7fffu + ((x >> 16) & 1u);
  return (unsigned short)(r >> 16);
}

typedef __attribute__((address_space(3))) unsigned int lds_uint;
typedef __attribute__((address_space(1))) const unsigned int glb_uint;
__device__ __forceinline__ void gload16(const void* g, void* l) {
  __builtin_amdgcn_global_load_lds((glb_uint*)g, (lds_uint*)l, 16, 0, 0);
}

// ---------------- embeds -> bf16 hi ----------------
__global__ __launch_bounds__(256) void split_embeds(const float* __restrict__ e,
                                                    unsigned short* __restrict__ ehi) {
  int gid = blockIdx.x * 256 + threadIdx.x;
  const float4* p = reinterpret_cast<const float4*>(e) + (size_t)gid * 2;
  float4 a = p[0], b = p[1];
  float f[8] = {a.x, a.y, a.z, a.w, b.x, b.y, b.z, b.w};
  unsigned short hi[8];
  #pragma unroll
  for (int i = 0; i < 8; ++i) hi[i] = bf16_rne(f[i]);
  us4 h0 = {hi[0], hi[1], hi[2], hi[3]}, h1 = {hi[4], hi[5], hi[6], hi[7]};
  *reinterpret_cast<us4*>(&ehi[(size_t)gid * 8]) = h0;
  *reinterpret_cast<us4*>(&ehi[(size_t)gid * 8 + 4]) = h1;
}

// ------------- padded W (L0: 6144 cols; L1 @0 + L2 @384 in W12: 512 cols) -------------
__global__ __launch_bounds__(256) void prep_w(const float* __restrict__ cb0,
                                              const float* __restrict__ cb1,
                                              const float* __restrict__ cb2,
                                              unsigned short* __restrict__ W0,
                                              unsigned short* __restrict__ W12,
                                              float* __restrict__ wsq0,
                                              float* __restrict__ wsq12) {
  int wv = threadIdx.x >> 6, ln = threadIdx.x & 63;
  int p = blockIdx.x * 4 + wv;                   // 0..6655
  const float* src = nullptr; int local = 0;
  unsigned short* dst; float* wdst; int dcol;
  if (p < 6144) {
    dst = W0; wdst = wsq0; dcol = p;
    if (p < 5832) { src = cb0; local = p; }
  } else {
    int q = p - 6144;                            // 0..511
    dst = W12; wdst = wsq12; dcol = q;
    if (q < 324) { src = cb1; local = q; }
    else if (q >= 384 && q < 402) { src = cb2; local = q - 384; }
  }
  float4 f = make_float4(0.f, 0.f, 0.f, 0.f);
  if (src) f = *reinterpret_cast<const float4*>(src + (size_t)local * DDIM + ln * 4);
  us4 h = {bf16_rne(f.x), bf16_rne(f.y), bf16_rne(f.z), bf16_rne(f.w)};
  *reinterpret_cast<us4*>(&dst[(size_t)dcol * DDIM + ln * 4]) = h;
  float s = f.x * f.x + f.y * f.y + f.z * f.z + f.w * f.w;
  #pragma unroll
  for (int m = 32; m > 0; m >>= 1) s += __shfl_xor(s, m);
  if (ln == 0) wdst[dcol] = src ? s : 1e38f;
}

// ------------- MFMA GEMM + in-lane packed-key top-2 scan -------------
// grid (128 rowblocks, 4 groups); 256 thr = 4 waves (2m x 2n); block 128 rows
// x 128 cols/iter; A full-K in VGPRs; B dbuf LDS; one merge per block.
__global__ __launch_bounds__(256, 2) void gemm_scan(
    const unsigned short* __restrict__ Ehi,
    const unsigned short* __restrict__ W0,
    const unsigned short* __restrict__ W12,
    const float* __restrict__ wsq0,
    const float* __restrict__ wsq12,
    float* __restrict__ ckeys) {
  __shared__ float smem[8704];                    // 34,816 B (16KB B-dbuf U merge buf)
  unsigned short* Bs = reinterpret_cast<unsigned short*>(smem);

  const int tid = threadIdx.x;
  const int wv = tid >> 6, ln = tid & 63;
  const int wm = wv >> 1, wn = wv & 1;
  const int t = ln & 15, lg = ln >> 4;
  const int rb = blockIdx.x, grp = blockIdx.y;

  const unsigned short* Wb; const float* wsqb; int nnt;
  if (grp == 0)      { Wb = W0;             wsqb = wsq0;        nnt = 24; }
  else if (grp == 1) { Wb = W0 + 3072*256;  wsqb = wsq0 + 3072; nnt = 24; }
  else if (grp == 2) { Wb = W12;            wsqb = wsq12;       nnt = 3;  }
  else               { Wb = W12 + 384*256;  wsqb = wsq12 + 384; nnt = 1;  }

  // A fragments: rows rb*128 + wm*64 + i*16 + t, k = ks*32 + lg*8
  bf16x8 af[4][8];
  {
    const unsigned short* abase = Ehi + (size_t)(rb * 128 + wm * 64 + t) * 256 + lg * 8;
    #pragma unroll
    for (int i = 0; i < 4; ++i)
      #pragma unroll
      for (int ks = 0; ks < 8; ++ks)
        af[i][ks] = *reinterpret_cast<const bf16x8*>(abase + i * 16 * 256 + ks * 32);
  }

  // staging source constants (both-sides chunk swizzle; LDS dest stays linear)
  int col_[2], cs_[2];
  #pragma unroll
  for (int c = 0; c < 2; ++c) {
    int chunk = c * 256 + tid;
    col_[c] = chunk >> 2;
    cs_[c]  = ((chunk & 3) ^ ((col_[c] >> 1) & 3)) * 8;
  }

#define STAGE(buf, cc) do {                                                   \
    const unsigned short* wsrc = Wb + ((cc) >> 3) * (128 * 256) + ((cc) & 7) * 32; \
    _Pragma("unroll")                                                         \
    for (int c = 0; c < 2; ++c)                                               \
      gload16(wsrc + (size_t)col_[c] * 256 + cs_[c],                          \
              Bs + (buf) * 4096 + (c * 256 + wv * 64) * 8);                   \
  } while (0)

  f32x4 acc[4][4];
  float s1[4][4], s2[4][4];
  #pragma unroll
  for (int i = 0; i < 4; ++i)
    #pragma unroll
    for (int r = 0; r < 4; ++r) { s1[i][r] = INFINITY; s2[i][r] = INFINITY; }
  #pragma unroll
  for (int i = 0; i < 4; ++i)
    #pragma unroll
    for (int j = 0; j < 4; ++j) acc[i][j] = (f32x4){0.f, 0.f, 0.f, 0.f};

  const int lastcc = nnt * 8 - 1;
  STAGE(0, 0);
  __syncthreads();
  for (int ntl = 0; ntl < nnt; ++ntl) {
    float wq[4];
    #pragma unroll
    for (int j = 0; j < 4; ++j) wq[j] = wsqb[ntl * 128 + wn * 64 + j * 16 + t];
    #pragma unroll
    for (int ks = 0; ks < 8; ++ks) {
      const int buf = ks & 1;
      const int cc = ntl * 8 + ks;
      if (cc < lastcc) STAGE(buf ^ 1, cc + 1);
      bf16x8 bfr[4];
      #pragma unroll
      for (int j = 0; j < 4; ++j) {
        int col = wn * 64 + j * 16 + t;
        bfr[j] = *reinterpret_cast<const bf16x8*>(
            Bs + buf * 4096 + col * 32 + ((lg ^ ((col >> 1) & 3)) << 3));
      }
      #pragma unroll
      for (int i = 0; i < 4; ++i)
        #pragma unroll
        for (int j = 0; j < 4; ++j)
          acc[i][j] = __builtin_amdgcn_mfma_f32_16x16x32_bf16(af[i][ks], bfr[j], acc[i][j], 0, 0, 0);
      if (ks < 7) __syncthreads();
    }
    // scan: key = (dist & ~0xFFF) | local_col_idx; float-min == lex (dist,idx)
    {
      const unsigned lbase = (unsigned)(ntl * 128 + wn * 64 + t);
      #pragma unroll
      for (int i = 0; i < 4; ++i)
        #pragma unroll
        for (int j = 0; j < 4; ++j) {
          const unsigned lidx = lbase + j * 16;
          #pragma unroll
          for (int r = 0; r < 4; ++r) {
            float dv = fmaf(-2.0f, acc[i][j][r], wq[j]);
            float key = __uint_as_float((__float_as_uint(dv) & 0xFFFFF000u) | lidx);
            float o1 = s1[i][r];
            s2[i][r] = __builtin_amdgcn_fmed3f(o1, s2[i][r], key);
            s1[i][r] = fminf(o1, key);
            acc[i][j][r] = 0.0f;
          }
        }
    }
    __syncthreads();
  }
#undef STAGE

  // merge: dump per-lane top-2 to LDS [128 rows][64 keys] (stride 68), then
  // 128 row-threads keep top-4 via min/med3 chain and write packed keys.
  #pragma unroll
  for (int i = 0; i < 4; ++i)
    #pragma unroll
    for (int r = 0; r < 4; ++r) {
      int rib = wm * 64 + i * 16 + lg * 4 + r;
      int slot = (wn * 16 + t) * 2;
      smem[rib * 68 + slot]     = s1[i][r];
      smem[rib * 68 + slot + 1] = s2[i][r];
    }
  __syncthreads();
  if (tid < 128) {
    float qd0 = INFINITY, qd1 = INFINITY, qd2 = INFINITY, qd3 = INFINITY;
    #pragma unroll
    for (int s = 0; s < 64; ++s) {
      float k = smem[tid * 68 + s];
      float o1 = qd0, o2 = qd1, o3 = qd2;
      qd0 = fminf(o1, k);
      qd1 = __builtin_amdgcn_fmed3f(o1, o2, k);
      qd2 = __builtin_amdgcn_fmed3f(o2, o3, k);
      qd3 = __builtin_amdgcn_fmed3f(o3, qd3, k);
    }
    float4 o = {qd0, qd1, qd2, qd3};
    *reinterpret_cast<float4*>(&ckeys[(size_t)(rb * 128 + tid) * 16 + grp * 4]) = o;
  }
}

// ------------- exact fp64 rescore of 4 candidates + gather + loss -------------
__global__ __launch_bounds__(256) void rescore(const float* __restrict__ embeds,
                                               const float* __restrict__ cb0,
                                               const float* __restrict__ cb1,
                                               const float* __restrict__ cb2,
                                               const float* __restrict__ ckeys,
                                               float* __restrict__ out,
                                               float* __restrict__ lossp) {
  const int wv = threadIdx.x >> 6, ln = threadIdx.x & 63;
  const int gid = blockIdx.x * 4 + wv;            // 0..49151
  const int layer = gid >> 14, row = gid & (NROWS - 1);
  const float* cb; int K, slot0, nslot;
  if (layer == 0)      { cb = cb0; K = 5832; slot0 = 0;  nslot = 8; }
  else if (layer == 1) { cb = cb1; K = 324;  slot0 = 8;  nslot = 4; }
  else                 { cb = cb2; K = 18;   slot0 = 12; nslot = 4; }

  // merge slots -> top-4 (quantized dist, global idx), first-index ties
  float qv[4] = {INFINITY, INFINITY, INFINITY, INFINITY};
  int   qi[4] = {0x7fffffff, 0x7fffffff, 0x7fffffff, 0x7fffffff};
  for (int s = 0; s < nslot; ++s) {
    unsigned kb = __float_as_uint(ckeys[(size_t)row * 16 + slot0 + s]);
    int lidx = (int)(kb & 0xFFFu);
    float d  = __uint_as_float(kb & 0xFFFFF000u);
    int g = (layer == 0 && s >= 4) ? (lidx + 3072) : lidx;
    bool b0 = (d < qv[0]) || (d == qv[0] && g < qi[0]);
    bool b1 = (d < qv[1]) || (d == qv[1] && g < qi[1]);
    bool b2 = (d < qv[2]) || (d == qv[2] && g < qi[2]);
    bool b3 = (d < qv[3]) || (d == qv[3] && g < qi[3]);
    qv[3] = b3 ? (b2 ? qv[2] : d) : qv[3];  qi[3] = b3 ? (b2 ? qi[2] : g) : qi[3];
    qv[2] = b2 ? (b1 ? qv[1] : d) : qv[2];  qi[2] = b2 ? (b1 ? qi[1] : g) : qi[2];
    qv[1] = b1 ? (b0 ? qv[0] : d) : qv[1];  qi[1] = b1 ? (b0 ? qi[0] : g) : qi[1];
    if (b0) { qv[0] = d; qi[0] = g; }
  }

  // 4 cand-groups x 16 lanes; lane covers dims [li*16, li*16+16)
  const int cg = ln >> 4, li = ln & 15;
  int ki = (cg == 0) ? qi[0] : (cg == 1) ? qi[1] : (cg == 2) ? qi[2] : qi[3];
  bool valid = (ki >= 0) && (ki < K);
  int ks = valid ? ki : 0;

  float4 e4[4], w4[4];
  #pragma unroll
  for (int q = 0; q < 4; ++q) {
    e4[q] = *reinterpret_cast<const float4*>(embeds + (size_t)row * DDIM + li * 16 + q * 4);
    w4[q] = *reinterpret_cast<const float4*>(cb + (size_t)ks * DDIM + li * 16 + q * 4);
  }
  double d = 0.0;
  #pragma unroll
  for (int q = 0; q < 4; ++q) {
    double x0 = (double)e4[q].x - (double)w4[q].x;
    double x1 = (double)e4[q].y - (double)w4[q].y;
    double x2 = (double)e4[q].z - (double)w4[q].z;
    double x3 = (double)e4[q].w - (double)w4[q].w;
    d += x0 * x0 + x1 * x1 + x2 * x2 + x3 * x3;
  }
  if (!valid) d = (double)INFINITY;
  #pragma unroll
  for (int m = 1; m < 16; m <<= 1) d += __shfl_xor(d, m);   // sum within cand-group

  double bd = d; int bk = valid ? ki : 0x7fffffff; int bcg = cg;
  #pragma unroll
  for (int m = 16; m < 64; m <<= 1) {                       // argmin across groups
    double od = __shfl_xor(bd, m);
    int ok  = __shfl_xor(bk, m);
    int ocg = __shfl_xor(bcg, m);
    bool better = (od < bd) || (od == bd && ok < bk);
    bd = better ? od : bd; bk = better ? ok : bk; bcg = better ? ocg : bcg;
  }
  if (bcg == cg) {                                          // winning group's 16 lanes write
    #pragma unroll
    for (int q = 0; q < 4; ++q)
      *reinterpret_cast<float4*>(out + (size_t)gid * DDIM + li * 16 + q * 4) = w4[q];
  }
  __shared__ float red[4];
  if (ln == 0) red[wv] = (float)bd;
  __syncthreads();
  if (threadIdx.x == 0) lossp[blockIdx.x] = red[0] + red[1] + red[2] + red[3];
}

__global__ __launch_bounds__(256) void loss_reduce(const float* __restrict__ lossp,
                                                   float* __restrict__ outloss) {
  __shared__ float red[256];
  const int tid = threadIdx.x;
  float s = 0.f;
  for (int i = tid; i < 12288; i += 256) s += lossp[i];
  red[tid] = s;
  __syncthreads();
  for (int st = 128; st > 0; st >>= 1) {
    if (tid < st) red[tid] += red[tid + st];
    __syncthreads();
  }
  if (tid == 0) outloss[0] = red[0] * (1.25f / ((float)NROWS * (float)DDIM));
}

extern "C" void kernel_launch(void* const* d_in, const int* in_sizes, int n_in,
                              void* d_out, int out_size, void* d_ws, size_t ws_size,
                              hipStream_t stream) {
  const float* embeds = (const float*)d_in[0];
  const float* cb0    = (const float*)d_in[1];
  const float* cb1    = (const float*)d_in[2];
  const float* cb2    = (const float*)d_in[3];
  float* out  = (float*)d_out;
  float* loss = out + (size_t)3 * NROWS * DDIM;

  char* ws = (char*)d_ws;
  unsigned short* Ehi  = (unsigned short*)(ws);               //  8,388,608 B
  unsigned short* W0   = (unsigned short*)(ws + 8388608);     //  3,145,728 B
  unsigned short* W12  = (unsigned short*)(ws + 11534336);    //    262,144 B
  float*          wsq0 = (float*)(ws + 11796480);             //     24,576 B
  float*          wsq12= (float*)(ws + 11821056);             //      2,048 B
  float*          ckeys= (float*)(ws + 11823104);             //  1,048,576 B
  float*          lp   = (float*)(ws + 12871680);             //     49,152 B

  (void)in_sizes; (void)n_in; (void)out_size; (void)ws_size;

  split_embeds<<<2048, 256, 0, stream>>>(embeds, Ehi);
  prep_w<<<1664, 256, 0, stream>>>(cb0, cb1, cb2, W0, W12, wsq0, wsq12);
  gemm_scan<<<dim3(128, 4), 256, 0, stream>>>(Ehi, W0, W12, wsq0, wsq12, ckeys);
  rescore<<<12288, 256, 0, stream>>>(embeds, cb0, cb1, cb2, ckeys, out, lp);
  loss_reduce<<<1, 256, 0, stream>>>(lp, loss);
}

// Round 5
// 183.124 us; speedup vs baseline: 1.9620x; 1.0143x over previous
//
#include <hip/hip_runtime.h>
#include <math.h>

#define NROWS 16384
#define DDIM  256

typedef __attribute__((ext_vector_type(8))) short bf16x8;
typedef __attribute__((ext_vector_type(4))) float f32x4;
typedef __attribute__((ext_vector_type(4))) unsigned short us4;

__device__ __forceinline__ unsigned short bf16_rne(float f) {
  unsigned x = __float_as_uint(f);
  unsigned r = x + 0x7fffu + ((x >> 16) & 1u);
  return (unsigned short)(r >> 16);
}

typedef __attribute__((address_space(3))) unsigned int lds_uint;
typedef __attribute__((address_space(1))) const unsigned int glb_uint;
__device__ __forceinline__ void gload16(const void* g, void* l) {
  __builtin_amdgcn_global_load_lds((glb_uint*)g, (lds_uint*)l, 16, 0, 0);
}

// ---------------- embeds -> bf16 hi ----------------
__global__ __launch_bounds__(256) void split_embeds(const float* __restrict__ e,
                                                    unsigned short* __restrict__ ehi) {
  int gid = blockIdx.x * 256 + threadIdx.x;
  const float4* p = reinterpret_cast<const float4*>(e) + (size_t)gid * 2;
  float4 a = p[0], b = p[1];
  float f[8] = {a.x, a.y, a.z, a.w, b.x, b.y, b.z, b.w};
  unsigned short hi[8];
  #pragma unroll
  for (int i = 0; i < 8; ++i) hi[i] = bf16_rne(f[i]);
  us4 h0 = {hi[0], hi[1], hi[2], hi[3]}, h1 = {hi[4], hi[5], hi[6], hi[7]};
  *reinterpret_cast<us4*>(&ehi[(size_t)gid * 8]) = h0;
  *reinterpret_cast<us4*>(&ehi[(size_t)gid * 8 + 4]) = h1;
}

// ------------- padded W (L0: 6144 cols; L1 @0 + L2 @384 in W12: 512 cols) -------------
__global__ __launch_bounds__(256) void prep_w(const float* __restrict__ cb0,
                                              const float* __restrict__ cb1,
                                              const float* __restrict__ cb2,
                                              unsigned short* __restrict__ W0,
                                              unsigned short* __restrict__ W12,
                                              float* __restrict__ wsq0,
                                              float* __restrict__ wsq12) {
  int wv = threadIdx.x >> 6, ln = threadIdx.x & 63;
  int p = blockIdx.x * 4 + wv;                   // 0..6655
  const float* src = nullptr; int local = 0;
  unsigned short* dst; float* wdst; int dcol;
  if (p < 6144) {
    dst = W0; wdst = wsq0; dcol = p;
    if (p < 5832) { src = cb0; local = p; }
  } else {
    int q = p - 6144;                            // 0..511
    dst = W12; wdst = wsq12; dcol = q;
    if (q < 324) { src = cb1; local = q; }
    else if (q >= 384 && q < 402) { src = cb2; local = q - 384; }
  }
  float4 f = make_float4(0.f, 0.f, 0.f, 0.f);
  if (src) f = *reinterpret_cast<const float4*>(src + (size_t)local * DDIM + ln * 4);
  us4 h = {bf16_rne(f.x), bf16_rne(f.y), bf16_rne(f.z), bf16_rne(f.w)};
  *reinterpret_cast<us4*>(&dst[(size_t)dcol * DDIM + ln * 4]) = h;
  float s = f.x * f.x + f.y * f.y + f.z * f.z + f.w * f.w;
  #pragma unroll
  for (int m = 32; m > 0; m >>= 1) s += __shfl_xor(s, m);
  if (ln == 0) wdst[dcol] = src ? s : 1e38f;
}

// ------------- MFMA GEMM + in-lane packed-key top-2 scan -------------
// grid (128 rowblocks, 10 colgroups): 8x768 cols of L0 (6 tiles), L1 (3), L2 (1).
// 256 thr = 4 waves (2m x 2n); 128 rows x 128 cols/iter; A full-K in VGPRs;
// B dbuf LDS; one cross-lane merge per block.
__global__ __launch_bounds__(256, 2) void gemm_scan(
    const unsigned short* __restrict__ Ehi,
    const unsigned short* __restrict__ W0,
    const unsigned short* __restrict__ W12,
    const float* __restrict__ wsq0,
    const float* __restrict__ wsq12,
    float* __restrict__ ckeys) {
  __shared__ float smem[8704];                    // 34,816 B (B-dbuf U merge buf)
  unsigned short* Bs = reinterpret_cast<unsigned short*>(smem);

  const int tid = threadIdx.x;
  const int wv = tid >> 6, ln = tid & 63;
  const int wm = wv >> 1, wn = wv & 1;
  const int t = ln & 15, lg = ln >> 4;
  const int rb = blockIdx.x, grp = blockIdx.y;

  const unsigned short* Wb; const float* wsqb; int nnt;
  if (grp < 8)       { Wb = W0 + (size_t)grp * 768 * 256; wsqb = wsq0 + grp * 768; nnt = 6; }
  else if (grp == 8) { Wb = W12;             wsqb = wsq12;       nnt = 3; }
  else               { Wb = W12 + 384 * 256; wsqb = wsq12 + 384; nnt = 1; }

  // A fragments: rows rb*128 + wm*64 + i*16 + t, k = ks*32 + lg*8
  bf16x8 af[4][8];
  {
    const unsigned short* abase = Ehi + (size_t)(rb * 128 + wm * 64 + t) * 256 + lg * 8;
    #pragma unroll
    for (int i = 0; i < 4; ++i)
      #pragma unroll
      for (int ks = 0; ks < 8; ++ks)
        af[i][ks] = *reinterpret_cast<const bf16x8*>(abase + i * 16 * 256 + ks * 32);
  }

  // staging source constants (both-sides chunk swizzle; LDS dest stays linear)
  int col_[2], cs_[2];
  #pragma unroll
  for (int c = 0; c < 2; ++c) {
    int chunk = c * 256 + tid;
    col_[c] = chunk >> 2;
    cs_[c]  = ((chunk & 3) ^ ((col_[c] >> 1) & 3)) * 8;
  }

#define STAGE(buf, cc) do {                                                   \
    const unsigned short* wsrc = Wb + ((cc) >> 3) * (128 * 256) + ((cc) & 7) * 32; \
    _Pragma("unroll")                                                         \
    for (int c = 0; c < 2; ++c)                                               \
      gload16(wsrc + (size_t)col_[c] * 256 + cs_[c],                          \
              Bs + (buf) * 4096 + (c * 256 + wv * 64) * 8);                   \
  } while (0)

  f32x4 acc[4][4];
  float s1[4][4], s2[4][4];
  #pragma unroll
  for (int i = 0; i < 4; ++i)
    #pragma unroll
    for (int r = 0; r < 4; ++r) { s1[i][r] = INFINITY; s2[i][r] = INFINITY; }
  #pragma unroll
  for (int i = 0; i < 4; ++i)
    #pragma unroll
    for (int j = 0; j < 4; ++j) acc[i][j] = (f32x4){0.f, 0.f, 0.f, 0.f};

  const int lastcc = nnt * 8 - 1;
  STAGE(0, 0);
  __syncthreads();
  for (int ntl = 0; ntl < nnt; ++ntl) {
    float wq[4];
    #pragma unroll
    for (int j = 0; j < 4; ++j) wq[j] = wsqb[ntl * 128 + wn * 64 + j * 16 + t];
    #pragma unroll
    for (int ks = 0; ks < 8; ++ks) {
      const int buf = ks & 1;
      const int cc = ntl * 8 + ks;
      if (cc < lastcc) STAGE(buf ^ 1, cc + 1);
      bf16x8 bfr[4];
      #pragma unroll
      for (int j = 0; j < 4; ++j) {
        int col = wn * 64 + j * 16 + t;
        bfr[j] = *reinterpret_cast<const bf16x8*>(
            Bs + buf * 4096 + col * 32 + ((lg ^ ((col >> 1) & 3)) << 3));
      }
      #pragma unroll
      for (int i = 0; i < 4; ++i)
        #pragma unroll
        for (int j = 0; j < 4; ++j)
          acc[i][j] = __builtin_amdgcn_mfma_f32_16x16x32_bf16(af[i][ks], bfr[j], acc[i][j], 0, 0, 0);
      if (ks < 7) __syncthreads();
    }
    // scan: key = (dist & ~0xFFF) | local_col_idx; float-min == lex (dist,idx)
    {
      const unsigned lbase = (unsigned)(ntl * 128 + wn * 64 + t);
      #pragma unroll
      for (int i = 0; i < 4; ++i)
        #pragma unroll
        for (int j = 0; j < 4; ++j) {
          const unsigned lidx = lbase + j * 16;
          #pragma unroll
          for (int r = 0; r < 4; ++r) {
            float dv = fmaf(-2.0f, acc[i][j][r], wq[j]);
            float key = __uint_as_float((__float_as_uint(dv) & 0xFFFFF000u) | lidx);
            float o1 = s1[i][r];
            s2[i][r] = __builtin_amdgcn_fmed3f(o1, s2[i][r], key);
            s1[i][r] = fminf(o1, key);
            acc[i][j][r] = 0.0f;
          }
        }
    }
    __syncthreads();
  }
#undef STAGE

  // merge: dump per-lane top-2 to LDS [128 rows][64 keys] (stride 68), then
  // 128 row-threads keep top-4 via min/med3 chain and write packed keys.
  #pragma unroll
  for (int i = 0; i < 4; ++i)
    #pragma unroll
    for (int r = 0; r < 4; ++r) {
      int rib = wm * 64 + i * 16 + lg * 4 + r;
      int slot = (wn * 16 + t) * 2;
      smem[rib * 68 + slot]     = s1[i][r];
      smem[rib * 68 + slot + 1] = s2[i][r];
    }
  __syncthreads();
  if (tid < 128) {
    float qd0 = INFINITY, qd1 = INFINITY, qd2 = INFINITY, qd3 = INFINITY;
    #pragma unroll
    for (int s = 0; s < 64; ++s) {
      float k = smem[tid * 68 + s];
      float o1 = qd0, o2 = qd1, o3 = qd2;
      qd0 = fminf(o1, k);
      qd1 = __builtin_amdgcn_fmed3f(o1, o2, k);
      qd2 = __builtin_amdgcn_fmed3f(o2, o3, k);
      qd3 = __builtin_amdgcn_fmed3f(o3, qd3, k);
    }
    float4 o = {qd0, qd1, qd2, qd3};
    *reinterpret_cast<float4*>(&ckeys[(size_t)(rb * 128 + tid) * 40 + grp * 4]) = o;
  }
}

// ------------- exact fp64 rescore of 4 candidates + gather + loss -------------
__global__ __launch_bounds__(256) void rescore(const float* __restrict__ embeds,
                                               const float* __restrict__ cb0,
                                               const float* __restrict__ cb1,
                                               const float* __restrict__ cb2,
                                               const float* __restrict__ ckeys,
                                               float* __restrict__ out,
                                               float* __restrict__ lossp) {
  const int wv = threadIdx.x >> 6, ln = threadIdx.x & 63;
  const int gid = blockIdx.x * 4 + wv;            // 0..49151
  const int layer = gid >> 14, row = gid & (NROWS - 1);
  const float* cb; int K, slot0, nslot;
  if (layer == 0)      { cb = cb0; K = 5832; slot0 = 0;  nslot = 32; }
  else if (layer == 1) { cb = cb1; K = 324;  slot0 = 32; nslot = 4; }
  else                 { cb = cb2; K = 18;   slot0 = 36; nslot = 4; }

  // merge slots -> top-4 (quantized dist, global idx), first-index ties
  float qv[4] = {INFINITY, INFINITY, INFINITY, INFINITY};
  int   qi[4] = {0x7fffffff, 0x7fffffff, 0x7fffffff, 0x7fffffff};
  for (int s = 0; s < nslot; ++s) {
    unsigned kb = __float_as_uint(ckeys[(size_t)row * 40 + slot0 + s]);
    int lidx = (int)(kb & 0xFFFu);
    float d  = __uint_as_float(kb & 0xFFFFF000u);
    int g = (layer == 0) ? ((s >> 2) * 768 + lidx) : lidx;
    bool b0 = (d < qv[0]) || (d == qv[0] && g < qi[0]);
    bool b1 = (d < qv[1]) || (d == qv[1] && g < qi[1]);
    bool b2 = (d < qv[2]) || (d == qv[2] && g < qi[2]);
    bool b3 = (d < qv[3]) || (d == qv[3] && g < qi[3]);
    qv[3] = b3 ? (b2 ? qv[2] : d) : qv[3];  qi[3] = b3 ? (b2 ? qi[2] : g) : qi[3];
    qv[2] = b2 ? (b1 ? qv[1] : d) : qv[2];  qi[2] = b2 ? (b1 ? qi[1] : g) : qi[2];
    qv[1] = b1 ? (b0 ? qv[0] : d) : qv[1];  qi[1] = b1 ? (b0 ? qi[0] : g) : qi[1];
    if (b0) { qv[0] = d; qi[0] = g; }
  }

  // 4 cand-groups x 16 lanes; lane covers dims [li*16, li*16+16)
  const int cg = ln >> 4, li = ln & 15;
  int ki = (cg == 0) ? qi[0] : (cg == 1) ? qi[1] : (cg == 2) ? qi[2] : qi[3];
  bool valid = (ki >= 0) && (ki < K);
  int ks = valid ? ki : 0;

  float4 e4[4], w4[4];
  #pragma unroll
  for (int q = 0; q < 4; ++q) {
    e4[q] = *reinterpret_cast<const float4*>(embeds + (size_t)row * DDIM + li * 16 + q * 4);
    w4[q] = *reinterpret_cast<const float4*>(cb + (size_t)ks * DDIM + li * 16 + q * 4);
  }
  double d = 0.0;
  #pragma unroll
  for (int q = 0; q < 4; ++q) {
    double x0 = (double)e4[q].x - (double)w4[q].x;
    double x1 = (double)e4[q].y - (double)w4[q].y;
    double x2 = (double)e4[q].z - (double)w4[q].z;
    double x3 = (double)e4[q].w - (double)w4[q].w;
    d += x0 * x0 + x1 * x1 + x2 * x2 + x3 * x3;
  }
  if (!valid) d = (double)INFINITY;
  #pragma unroll
  for (int m = 1; m < 16; m <<= 1) d += __shfl_xor(d, m);   // sum within cand-group

  double bd = d; int bk = valid ? ki : 0x7fffffff; int bcg = cg;
  #pragma unroll
  for (int m = 16; m < 64; m <<= 1) {                       // argmin across groups
    double od = __shfl_xor(bd, m);
    int ok  = __shfl_xor(bk, m);
    int ocg = __shfl_xor(bcg, m);
    bool better = (od < bd) || (od == bd && ok < bk);
    bd = better ? od : bd; bk = better ? ok : bk; bcg = better ? ocg : bcg;
  }
  if (bcg == cg) {                                          // winning group's 16 lanes write
    #pragma unroll
    for (int q = 0; q < 4; ++q)
      *reinterpret_cast<float4*>(out + (size_t)gid * DDIM + li * 16 + q * 4) = w4[q];
  }
  __shared__ float red[4];
  if (ln == 0) red[wv] = (float)bd;
  __syncthreads();
  if (threadIdx.x == 0) lossp[blockIdx.x] = red[0] + red[1] + red[2] + red[3];
}

__global__ __launch_bounds__(256) void loss_reduce(const float* __restrict__ lossp,
                                                   float* __restrict__ outloss) {
  __shared__ float red[256];
  const int tid = threadIdx.x;
  float s = 0.f;
  for (int i = tid; i < 12288; i += 256) s += lossp[i];
  red[tid] = s;
  __syncthreads();
  for (int st = 128; st > 0; st >>= 1) {
    if (tid < st) red[tid] += red[tid + st];
    __syncthreads();
  }
  if (tid == 0) outloss[0] = red[0] * (1.25f / ((float)NROWS * (float)DDIM));
}

extern "C" void kernel_launch(void* const* d_in, const int* in_sizes, int n_in,
                              void* d_out, int out_size, void* d_ws, size_t ws_size,
                              hipStream_t stream) {
  const float* embeds = (const float*)d_in[0];
  const float* cb0    = (const float*)d_in[1];
  const float* cb1    = (const float*)d_in[2];
  const float* cb2    = (const float*)d_in[3];
  float* out  = (float*)d_out;
  float* loss = out + (size_t)3 * NROWS * DDIM;

  char* ws = (char*)d_ws;
  unsigned short* Ehi  = (unsigned short*)(ws);               //  8,388,608 B
  unsigned short* W0   = (unsigned short*)(ws + 8388608);     //  3,145,728 B
  unsigned short* W12  = (unsigned short*)(ws + 11534336);    //    262,144 B
  float*          wsq0 = (float*)(ws + 11796480);             //     24,576 B
  float*          wsq12= (float*)(ws + 11821056);             //      2,048 B
  float*          ckeys= (float*)(ws + 11823104);             //  2,621,440 B
  float*          lp   = (float*)(ws + 14444544);             //     49,152 B

  (void)in_sizes; (void)n_in; (void)out_size; (void)ws_size;

  split_embeds<<<2048, 256, 0, stream>>>(embeds, Ehi);
  prep_w<<<1664, 256, 0, stream>>>(cb0, cb1, cb2, W0, W12, wsq0, wsq12);
  gemm_scan<<<dim3(128, 10), 256, 0, stream>>>(Ehi, W0, W12, wsq0, wsq12, ckeys);
  rescore<<<12288, 256, 0, stream>>>(embeds, cb0, cb1, cb2, ckeys, out, lp);
  loss_reduce<<<1, 256, 0, stream>>>(lp, loss);
}